// Round 2
// baseline (476.604 us; speedup 1.0000x reference)
//
#include <hip/hip_runtime.h>

// SimpleRNN fused kernel for MI355X (gfx950).
// B=256, T=512, I=64, H=256, O=1, fp32.
//
// Decomposition: 256 blocks (one per batch row) x 1024 threads.
// R2: 4-way k-split. Lane (j = tid>>2, q = tid&3) owns
// W_hh[j][q*64 .. +63] (64 VGPRs) and W_ih[j][q*16 .. +15] (16 VGPRs).
// Rationale: R1 left us at OccupancyPercent=23 (2 waves/SIMD) and 2440
// cyc/step vs the 640 cyc/step FMA-issue floor -- latency-bound. 4-way
// split doubles waves/SIMD (4), halves each thread's dependent FMA chain,
// and halves per-thread LDS reads. Total FMA work unchanged.
//
// LDS banking (keeps R1's zero-conflict property):
//   h: quarter q at float offset q*68  -> per-instr banks 4c+{0,4,8,12}, disjoint
//   x: quarter q at float offset q*20  -> per-instr banks 4c+{0,8,20,28}, disjoint
// All lanes sharing a quarter read the same address -> broadcast.

#define RNN_B 256
#define RNN_T 512
#define RNN_I 64
#define RNN_H 256

#define QH 68   // float stride between h quarters (64 + 4 pad)
#define QX 20   // float stride between x quarters (16 + 4 pad)

__global__ __launch_bounds__(1024, 4)
void rnn_fused_kernel(const float* __restrict__ x,     // [B,T,I]
                      const float* __restrict__ W_ih,  // [H,I]
                      const float* __restrict__ W_hh,  // [H,H]
                      const float* __restrict__ b_ih,  // [H]
                      const float* __restrict__ b_hh,  // [H]
                      const float* __restrict__ fc_W,  // [O,H], O=1
                      const float* __restrict__ fc_b,  // [O]
                      float* __restrict__ out)         // [B,O]
{
    const int b   = blockIdx.x;
    const int tid = threadIdx.x;   // 0..1023
    const int j   = tid >> 2;      // output hidden index 0..255
    const int q   = tid & 3;       // which quarter of the k-reduction

    __shared__ float hbuf[2][4 * QH];   // double-buffered hidden state (padded)
    __shared__ float xbuf[2][4 * QX];   // double-buffered x_t (padded)
    __shared__ float red[16];           // final block reduction

    // padded write index for h[j]: slot of float k is (k>>6)*QH + (k&63)
    const int jslot = (j >> 6) * QH + (j & 63);
    // padded float4 write index for x staging (valid for tid<16):
    // float4 #t covers floats 4t..4t+3 -> slot (t>>2)*QX + 4*(t&3)
    const int xslot = (tid >> 2) * QX + ((tid & 3) << 2);

    // ---- register-resident weights ----
    float4 wh[16];  // W_hh[j][q*64 + 4c + {0..3}]
    float4 wi[4];   // W_ih[j][q*16 + 4c + {0..3}]
    {
        const float4* src = reinterpret_cast<const float4*>(W_hh + j * RNN_H + q * 64);
        #pragma unroll
        for (int c = 0; c < 16; ++c) wh[c] = src[c];
        const float4* s2 = reinterpret_cast<const float4*>(W_ih + j * RNN_I + q * 16);
        #pragma unroll
        for (int c = 0; c < 4; ++c) wi[c] = s2[c];
    }
    const float bias2 = b_ih[j] + b_hh[j];
    const float fcw   = fc_W[j];

    // ---- prologue: h0 = 0, stage x[b,0,:] ----
    if (q == 0) hbuf[0][jslot] = 0.0f;
    if (tid < 16) {
        const float4* xs = reinterpret_cast<const float4*>(x + (size_t)b * RNN_T * RNN_I);
        *reinterpret_cast<float4*>(&xbuf[0][xslot]) = xs[tid];
    }
    __syncthreads();

    float hj = 0.0f;  // this lane's h_new[j] (identical within each 4-lane group)

#define RNN_STEP(CUR, NXT, TT)                                                  \
    {                                                                           \
        float4 xpre;                                                            \
        const bool doPre = (tid < 16) && ((TT) + 1 < RNN_T);                    \
        if (doPre) {                                                            \
            xpre = reinterpret_cast<const float4*>(                             \
                       x + ((size_t)b * RNN_T + ((TT) + 1)) * RNN_I)[tid];      \
        }                                                                       \
        float a0 = 0.f, a1 = 0.f, a2 = 0.f, a3 = 0.f;                           \
        const float4* hs = reinterpret_cast<const float4*>(&hbuf[CUR][q * QH]); \
        _Pragma("unroll")                                                       \
        for (int c = 0; c < 16; ++c) {                                          \
            const float4 h4 = hs[c];   /* broadcast; quarters on disjoint banks */ \
            a0 = fmaf(h4.x, wh[c].x, a0);                                       \
            a1 = fmaf(h4.y, wh[c].y, a1);                                       \
            a2 = fmaf(h4.z, wh[c].z, a2);                                       \
            a3 = fmaf(h4.w, wh[c].w, a3);                                       \
        }                                                                       \
        const float4* xs4 = reinterpret_cast<const float4*>(&xbuf[CUR][q * QX]);\
        _Pragma("unroll")                                                       \
        for (int c = 0; c < 4; ++c) {                                           \
            const float4 x4 = xs4[c];                                           \
            a0 = fmaf(x4.x, wi[c].x, a0);                                       \
            a1 = fmaf(x4.y, wi[c].y, a1);                                       \
            a2 = fmaf(x4.z, wi[c].z, a2);                                       \
            a3 = fmaf(x4.w, wi[c].w, a3);                                       \
        }                                                                       \
        float partial = (a0 + a1) + (a2 + a3);                                  \
        partial += __shfl_xor(partial, 1, 64);  /* combine quarter pairs   */   \
        partial += __shfl_xor(partial, 2, 64);  /* combine across pairs    */   \
        const float z  = partial + bias2;                                       \
        const float zc = fminf(fmaxf(z, -10.f), 10.f);                          \
        const float e  = exp2f(zc * 2.8853900817779268f);  /* e^(2z) */         \
        const float hn = (e - 1.f) * __builtin_amdgcn_rcpf(e + 1.f);            \
        hj = hn;                                                                \
        if (q == 0) hbuf[NXT][jslot] = hn;                                      \
        if (doPre) *reinterpret_cast<float4*>(&xbuf[NXT][xslot]) = xpre;        \
        __syncthreads();                                                        \
    }

    // t-loop unrolled x2: removes the per-step buffer-select cndmasks
    for (int t = 0; t < RNN_T; t += 2) {
        RNN_STEP(0, 1, t)
        RNN_STEP(1, 0, t + 1)
    }
#undef RNN_STEP

    // ---- epilogue: out[b] = sum_j h_T[j]*fc_W[j] + fc_b ----
    float term = (q == 0) ? hj * fcw : 0.0f;
    #pragma unroll
    for (int s = 1; s < 64; s <<= 1) term += __shfl_xor(term, s, 64);
    const int wid = tid >> 6;
    if ((tid & 63) == 0) red[wid] = term;
    __syncthreads();
    if (tid == 0) {
        float s = 0.f;
        #pragma unroll
        for (int w = 0; w < 16; ++w) s += red[w];
        out[b] = s + fc_b[0];
    }
}

extern "C" void kernel_launch(void* const* d_in, const int* in_sizes, int n_in,
                              void* d_out, int out_size, void* d_ws, size_t ws_size,
                              hipStream_t stream) {
    const float* x    = (const float*)d_in[0];
    const float* W_ih = (const float*)d_in[1];
    const float* W_hh = (const float*)d_in[2];
    const float* b_ih = (const float*)d_in[3];
    const float* b_hh = (const float*)d_in[4];
    const float* fc_W = (const float*)d_in[5];
    const float* fc_b = (const float*)d_in[6];
    float* out = (float*)d_out;

    rnn_fused_kernel<<<RNN_B, 1024, 0, stream>>>(x, W_ih, W_hh, b_ih, b_hh, fc_W, fc_b, out);
}

// Round 3
// 455.338 us; speedup vs baseline: 1.0467x; 1.0467x over previous
//
#include <hip/hip_runtime.h>

// SimpleRNN fused kernel for MI355X (gfx950).
// B=256, T=512, I=64, H=256, O=1, fp32.
//
// Decomposition: 256 blocks (one per batch row) x 512 threads.
// Lane (j = tid>>1, half = tid&1) owns W_hh[j][half*128 .. +127] (128 VGPRs)
// and W_ih[j][half*32 .. +31] (32 VGPRs). h is broadcast via LDS
// (double-buffered, one barrier per step). No cross-block communication.
//
// R1: padded LDS half-split (conflicts 1.34e8 -> 0, 608 -> 461 us).
// R2 (4-way split, 1024 thr) REGRESSED: occupancy doubled but time rose --
//    we are not latency-bound on waves.
// R3: the real limiter found via VGPR_Count=104 (R1) / 64 (R2), both far
//    below the declared weight footprint (160 floats R1). The register
//    allocator was rematerializing the loop-invariant weight loads as
//    per-step reloads from L1/L2 (320 KB/CU/step of cache traffic + vmcnt
//    stalls on the critical path every one of 512 steps). Fix: raise the
//    register budget with __launch_bounds__(512, 1) so W_hh/W_ih truly
//    stay in VGPRs (backend still caps at 256 regs since a 512-thread
//    block needs 2 waves/SIMD). Verification metric: VGPR_Count >= ~170.

#define RNN_B 256
#define RNN_T 512
#define RNN_I 64
#define RNN_H 256

// padded layouts: h[0..127] at [0..127], h[128..255] at [132..259]
//                 x[0..31]  at [0..31],  x[32..63]   at [36..67]
#define HSTRIDE 132   // float offset of half-1 h data
#define XSTRIDE 36    // float offset of half-1 x data

__global__ __launch_bounds__(512, 1)
void rnn_fused_kernel(const float* __restrict__ x,     // [B,T,I]
                      const float* __restrict__ W_ih,  // [H,I]
                      const float* __restrict__ W_hh,  // [H,H]
                      const float* __restrict__ b_ih,  // [H]
                      const float* __restrict__ b_hh,  // [H]
                      const float* __restrict__ fc_W,  // [O,H], O=1
                      const float* __restrict__ fc_b,  // [O]
                      float* __restrict__ out)         // [B,O]
{
    const int b    = blockIdx.x;
    const int tid  = threadIdx.x;   // 0..511
    const int j    = tid >> 1;      // output hidden index 0..255
    const int half = tid & 1;       // which half of the k-reduction

    __shared__ float hbuf[2][260];     // double-buffered hidden state (padded)
    __shared__ float xbuf[2][68];      // double-buffered x_t (padded)
    __shared__ float red[8];           // final block reduction

    // padded write index for h[j]
    const int jofs = j + ((j >> 7) << 2);          // j<128 -> j, else j+4
    // padded float4 write index for x staging (valid for tid<16)
    const int xofs = (tid << 2) + (((tid >> 3) & 1) << 2);

    // ---- register-resident weights (160 VGPRs; launch_bounds gives budget) ----
    float4 wh[32];  // W_hh[j][half*128 + 4c + {0..3}]
    float4 wi[8];   // W_ih[j][half*32  + 4c + {0..3}]
    {
        const float4* src = reinterpret_cast<const float4*>(W_hh + j * RNN_H + half * 128);
        #pragma unroll
        for (int c = 0; c < 32; ++c) wh[c] = src[c];
        const float4* s2 = reinterpret_cast<const float4*>(W_ih + j * RNN_I + half * 32);
        #pragma unroll
        for (int c = 0; c < 8; ++c) wi[c] = s2[c];
    }
    const float bias2 = b_ih[j] + b_hh[j];
    const float fcw   = fc_W[j];

    // ---- prologue: h0 = 0, stage x[b,0,:] ----
    if (half == 0) hbuf[0][jofs] = 0.0f;
    if (tid < 16) {
        const float4* xs = reinterpret_cast<const float4*>(x + (size_t)b * RNN_T * RNN_I);
        *reinterpret_cast<float4*>(&xbuf[0][xofs]) = xs[tid];
    }
    __syncthreads();

    float hj = 0.0f;  // this lane's h_new[j] (identical in lane pairs)

#define RNN_STEP(CUR, NXT, TT)                                                   \
    {                                                                            \
        float4 xpre;                                                             \
        const bool doPre = (tid < 16) && ((TT) + 1 < RNN_T);                     \
        if (doPre) {                                                             \
            xpre = reinterpret_cast<const float4*>(                              \
                       x + ((size_t)b * RNN_T + ((TT) + 1)) * RNN_I)[tid];       \
        }                                                                        \
        float a0 = 0.f, a1 = 0.f, a2 = 0.f, a3 = 0.f;                            \
        const float4* hs = reinterpret_cast<const float4*>(&hbuf[CUR][half * HSTRIDE]); \
        _Pragma("unroll")                                                        \
        for (int c = 0; c < 32; ++c) {                                           \
            const float4 h4 = hs[c];   /* broadcast; halves on disjoint banks */ \
            a0 = fmaf(h4.x, wh[c].x, a0);                                        \
            a1 = fmaf(h4.y, wh[c].y, a1);                                        \
            a2 = fmaf(h4.z, wh[c].z, a2);                                        \
            a3 = fmaf(h4.w, wh[c].w, a3);                                        \
        }                                                                        \
        const float4* xs4 = reinterpret_cast<const float4*>(&xbuf[CUR][half * XSTRIDE]); \
        _Pragma("unroll")                                                        \
        for (int c = 0; c < 8; ++c) {                                            \
            const float4 x4 = xs4[c];                                            \
            a0 = fmaf(x4.x, wi[c].x, a0);                                        \
            a1 = fmaf(x4.y, wi[c].y, a1);                                        \
            a2 = fmaf(x4.z, wi[c].z, a2);                                        \
            a3 = fmaf(x4.w, wi[c].w, a3);                                        \
        }                                                                        \
        float partial = (a0 + a1) + (a2 + a3);                                   \
        partial += __shfl_xor(partial, 1, 64);   /* add partner half's partial */\
        const float z  = partial + bias2;                                        \
        const float zc = fminf(fmaxf(z, -10.f), 10.f);                           \
        const float e  = exp2f(zc * 2.8853900817779268f);     /* e^(2z) */       \
        const float hn = (e - 1.f) * __builtin_amdgcn_rcpf(e + 1.f);             \
        hj = hn;                                                                 \
        if (half == 0) hbuf[NXT][jofs] = hn;                                     \
        if (doPre) *reinterpret_cast<float4*>(&xbuf[NXT][xofs]) = xpre;          \
        __syncthreads();                                                         \
    }

    // t-loop unrolled x2: removes the per-step buffer-select on hbuf/xbuf
    for (int t = 0; t < RNN_T; t += 2) {
        RNN_STEP(0, 1, t)
        RNN_STEP(1, 0, t + 1)
    }
#undef RNN_STEP

    // ---- epilogue: out[b] = sum_j h_T[j]*fc_W[j] + fc_b ----
    float term = (half == 0) ? hj * fcw : 0.0f;
    #pragma unroll
    for (int s = 1; s < 64; s <<= 1) term += __shfl_xor(term, s, 64);
    const int wid = tid >> 6;
    if ((tid & 63) == 0) red[wid] = term;
    __syncthreads();
    if (tid == 0) {
        float s = 0.f;
        #pragma unroll
        for (int w = 0; w < 8; ++w) s += red[w];
        out[b] = s + fc_b[0];
    }
}

extern "C" void kernel_launch(void* const* d_in, const int* in_sizes, int n_in,
                              void* d_out, int out_size, void* d_ws, size_t ws_size,
                              hipStream_t stream) {
    const float* x    = (const float*)d_in[0];
    const float* W_ih = (const float*)d_in[1];
    const float* W_hh = (const float*)d_in[2];
    const float* b_ih = (const float*)d_in[3];
    const float* b_hh = (const float*)d_in[4];
    const float* fc_W = (const float*)d_in[5];
    const float* fc_b = (const float*)d_in[6];
    float* out = (float*)d_out;

    rnn_fused_kernel<<<RNN_B, 512, 0, stream>>>(x, W_ih, W_hh, b_ih, b_hh, fc_W, fc_b, out);
}